// Round 7
// baseline (6250.482 us; speedup 1.0000x reference)
//
#include <hip/hip_runtime.h>
#include <hip/hip_bf16.h>

// MLA prefill: B=2,S=2048,D=2048,H=16,DQK=128(=64 nope+64 rope),DV=128,QLR=1536,KVLR=1024
// INPUTS ARE FP32 (per reference setup_inputs dtypes); OUTPUT FP32.
// Compute in bf16 MFMA (fp32 accum); fp32->bf16 conversion fused into GEMM
// LDS staging. Comparison is at bf16 precision w/ 2% threshold -> bf16 compute OK.
// No __expf (container-killer, R2-R4). No INFINITY (kept from R5; harmless).
//
// Workspace (42.5 MiB):
//   kv2  @ 0          (4096x3072 bf16, 25.2MB)   live: kv2-gemm .. attn
//   kpe  @ 25165824   (4096x64  bf16,  0.5MB)    live: rope_k .. attn
//   X    @ 25690112   (16.8MB region, time-shared)
//        kvb  (4096x1088 bf16)  live: kvb-gemm .. kv2-gemm
//        qa   (4096x1536 bf16)  live: qa-gemm .. qbuf-gemm
//        attno(4096x2048 bf16)  live: attn .. out-gemm
//   qbuf (4096x2048 bf16, 16.8MB) lives in d_out (33.5MB fp32) until out-gemm.

using bf16 = __hip_bfloat16;
typedef __attribute__((ext_vector_type(8))) short bf16x8;
typedef __attribute__((ext_vector_type(4))) float f32x4;

#define S_ 2048
#define NEG_BIG (-1e30f)

static __device__ __forceinline__ f32x4 mfma16(bf16x8 a, bf16x8 b, f32x4 c) {
    return __builtin_amdgcn_mfma_f32_16x16x32_bf16(a, b, c, 0, 0, 0);
}

// convert 8 contiguous fp32 -> 8 bf16 in registers
static __device__ __forceinline__ void cvt8(const float* __restrict__ p, bf16* __restrict__ dst) {
    float4 f0 = *(const float4*)p;
    float4 f1 = *(const float4*)(p + 4);
    dst[0] = (bf16)f0.x; dst[1] = (bf16)f0.y; dst[2] = (bf16)f0.z; dst[3] = (bf16)f0.w;
    dst[4] = (bf16)f1.x; dst[5] = (bf16)f1.y; dst[6] = (bf16)f1.z; dst[7] = (bf16)f1.w;
}

// ---------------------------------------------------------------------------
// GEMM: C[M,N] = A[M,K] @ B[N,K]^T. 128x128 tile, BK=32, 256 thr.
// A/B may be fp32 (converted to bf16 during LDS staging) or bf16.
// C stored fp32 or bf16. LDS XOR swizzle: chunkE = chunk ^ ((row>>1)&3).
// ---------------------------------------------------------------------------
template <bool A_F32, bool B_F32, bool C_F32>
__global__ __launch_bounds__(256) void gemm_bt(const void* __restrict__ Av,
                                               const void* __restrict__ Bv,
                                               void* __restrict__ Cv,
                                               int M, int N, int K,
                                               int lda, int ldb, int ldc) {
    __shared__ bf16 As[128 * 32];
    __shared__ bf16 Bs[128 * 32];
    const int tid = threadIdx.x;
    const int m0 = blockIdx.x * 128;
    const int n0 = blockIdx.y * 128;
    const int w = tid >> 6, lane = tid & 63, quad = lane >> 4, l15 = lane & 15;
    const int wr = (w >> 1) * 64, wc = (w & 1) * 64;

    f32x4 acc[4][4];
#pragma unroll
    for (int i = 0; i < 4; i++)
#pragma unroll
        for (int j = 0; j < 4; j++) acc[i][j] = (f32x4){0.f, 0.f, 0.f, 0.f};

    for (int k0 = 0; k0 < K; k0 += 32) {
        __syncthreads();
#pragma unroll
        for (int cc = 0; cc < 2; cc++) {
            int c = tid + cc * 256;          // 512 chunks of 8 elems
            int row = c >> 2;
            int chunk = c & 3;
            int chunkE = chunk ^ ((row >> 1) & 3);
            // A chunk
            if (A_F32) {
                alignas(16) bf16 tmp[8];
                cvt8((const float*)Av + (size_t)(m0 + row) * lda + k0 + chunk * 8, tmp);
                *(int4*)(&As[row * 32 + chunkE * 8]) = *(const int4*)tmp;
            } else {
                int4 va = *(const int4*)((const bf16*)Av + (size_t)(m0 + row) * lda + k0 + chunk * 8);
                *(int4*)(&As[row * 32 + chunkE * 8]) = va;
            }
            // B chunk (guarded rows)
            if (n0 + row < N) {
                if (B_F32) {
                    alignas(16) bf16 tmp[8];
                    cvt8((const float*)Bv + (size_t)(n0 + row) * ldb + k0 + chunk * 8, tmp);
                    *(int4*)(&Bs[row * 32 + chunkE * 8]) = *(const int4*)tmp;
                } else {
                    int4 vb = *(const int4*)((const bf16*)Bv + (size_t)(n0 + row) * ldb + k0 + chunk * 8);
                    *(int4*)(&Bs[row * 32 + chunkE * 8]) = vb;
                }
            } else {
                *(int4*)(&Bs[row * 32 + chunkE * 8]) = (int4){0, 0, 0, 0};
            }
        }
        __syncthreads();
        bf16x8 af[4], bfr[4];
#pragma unroll
        for (int mi = 0; mi < 4; mi++) {
            int row = wr + mi * 16 + l15;
            int chunkE = quad ^ ((row >> 1) & 3);
            af[mi] = *(const bf16x8*)(&As[row * 32 + chunkE * 8]);
        }
#pragma unroll
        for (int ni = 0; ni < 4; ni++) {
            int row = wc + ni * 16 + l15;
            int chunkE = quad ^ ((row >> 1) & 3);
            bfr[ni] = *(const bf16x8*)(&Bs[row * 32 + chunkE * 8]);
        }
#pragma unroll
        for (int mi = 0; mi < 4; mi++)
#pragma unroll
            for (int ni = 0; ni < 4; ni++)
                acc[mi][ni] = mfma16(af[mi], bfr[ni], acc[mi][ni]);
    }

#pragma unroll
    for (int mi = 0; mi < 4; mi++) {
#pragma unroll
        for (int ni = 0; ni < 4; ni++) {
            int col = n0 + wc + ni * 16 + l15;
            if (col < N) {
#pragma unroll
                for (int r = 0; r < 4; r++) {
                    int row = m0 + wr + mi * 16 + quad * 4 + r;
                    if (C_F32) ((float*)Cv)[(size_t)row * ldc + col] = acc[mi][ni][r];
                    else       ((bf16*)Cv)[(size_t)row * ldc + col] = (bf16)acc[mi][ni][r];
                }
            }
        }
    }
}

// ---------------------------------------------------------------------------
// In-place row RMSNorm on bf16 buffer, fp32 weight, fp32 stats.
// ---------------------------------------------------------------------------
__global__ void rmsnorm_ip(bf16* __restrict__ buf, const float* __restrict__ w,
                           int cols, int ld) {
    int row = blockIdx.x;
    bf16* p = buf + (size_t)row * ld;
    float ss = 0.f;
    for (int c = threadIdx.x; c < cols; c += 256) {
        float v = __bfloat162float(p[c]);
        ss += v * v;
    }
#pragma unroll
    for (int off = 32; off; off >>= 1) ss += __shfl_down(ss, off, 64);
    __shared__ float red[4];
    __shared__ float rnorm_s;
    if ((threadIdx.x & 63) == 0) red[threadIdx.x >> 6] = ss;
    __syncthreads();
    if (threadIdx.x == 0)
        rnorm_s = rsqrtf((red[0] + red[1] + red[2] + red[3]) / cols + 1e-6f);
    __syncthreads();
    float rn = rnorm_s;
    for (int c = threadIdx.x; c < cols; c += 256) {
        float v = __bfloat162float(p[c]);
        p[c] = (bf16)(v * rn * w[c]);
    }
}

// ---------------------------------------------------------------------------
// RoPE on k_pe: kpe[row,0..64) = rope(kvb[row,1024..1088)). fp32 freqs.
// ---------------------------------------------------------------------------
__global__ void rope_k(const bf16* __restrict__ kvb, bf16* __restrict__ kpe,
                       const float* __restrict__ fc, const float* __restrict__ fs) {
    int id = blockIdx.x * 256 + threadIdx.x;  // ROWS*32
    int row = id >> 5, i = id & 31;
    int s = row & (S_ - 1);
    const bf16* p = kvb + (size_t)row * 1088 + 1024 + 2 * i;
    float x0 = __bfloat162float(p[0]), x1 = __bfloat162float(p[1]);
    float c = fc[s * 32 + i], sn = fs[s * 32 + i];
    bf16* q = kpe + (size_t)row * 64 + 2 * i;
    q[0] = (bf16)(x0 * c - x1 * sn);
    q[1] = (bf16)(x0 * sn + x1 * c);
}

// RoPE on q_pe, in-place on bf16 qbuf: [row, h*128+64 .. h*128+128)
__global__ void rope_q(bf16* __restrict__ qb, const float* __restrict__ fc,
                       const float* __restrict__ fs) {
    int id = blockIdx.x * 256 + threadIdx.x;  // ROWS*16*32
    int row = id >> 9, rest = id & 511, h = rest >> 5, i = rest & 31;
    int s = row & (S_ - 1);
    bf16* p = qb + (size_t)row * 2048 + h * 128 + 64 + 2 * i;
    float x0 = __bfloat162float(p[0]), x1 = __bfloat162float(p[1]);
    float c = fc[s * 32 + i], sn = fs[s * 32 + i];
    p[0] = (bf16)(x0 * c - x1 * sn);
    p[1] = (bf16)(x0 * sn + x1 * c);
}

// ---------------------------------------------------------------------------
// Conservative attention: one wave per (b,h,s) query row. Lane j owns dims
// {j, j+64} of Q/K dot and V/O accum. Butterfly reduce; scalar online softmax.
// ---------------------------------------------------------------------------
__global__ __launch_bounds__(256) void attn_simple(const bf16* __restrict__ Qg,
                                                   const bf16* __restrict__ KV2,
                                                   const bf16* __restrict__ KPE,
                                                   bf16* __restrict__ Og) {
    const int wid = blockIdx.x * 4 + (threadIdx.x >> 6);  // 0 .. B*H*S-1
    const int lane = threadIdx.x & 63;
    const int b = wid >> 15;          // H*S = 32768
    const int rem = wid & 32767;
    const int h = rem >> 11;          // S = 2048
    const int s = rem & 2047;
    const float scale = 0.08838834764831845f;  // 1/sqrt(128)

    const bf16* qrow = Qg + ((size_t)(b * S_) + s) * 2048 + h * 128;
    const float q0 = __bfloat162float(qrow[lane]);
    const float q1 = __bfloat162float(qrow[64 + lane]);
    const bf16* Kn = KV2 + (size_t)(b * S_) * 3072 + h * 192;
    const bf16* Vv = Kn + 64;
    const bf16* Kp = KPE + (size_t)(b * S_) * 64;

    float m = NEG_BIG, l = 0.f, a0 = 0.f, a1 = 0.f;
    for (int t = 0; t <= s; t++) {
        float k0 = __bfloat162float(Kn[(size_t)t * 3072 + lane]);
        float k1 = __bfloat162float(Kp[(size_t)t * 64 + lane]);
        float part = q0 * k0 + q1 * k1;
        part += __shfl_xor(part, 1, 64);
        part += __shfl_xor(part, 2, 64);
        part += __shfl_xor(part, 4, 64);
        part += __shfl_xor(part, 8, 64);
        part += __shfl_xor(part, 16, 64);
        part += __shfl_xor(part, 32, 64);
        float x = part * scale;
        float mn = fmaxf(m, x);
        float alpha = expf(m - mn);
        float p = expf(x - mn);
        m = mn;
        l = l * alpha + p;
        float v0 = __bfloat162float(Vv[(size_t)t * 3072 + lane]);
        float v1 = __bfloat162float(Vv[(size_t)t * 3072 + 64 + lane]);
        a0 = a0 * alpha + p * v0;
        a1 = a1 * alpha + p * v1;
    }
    bf16* orow = Og + ((size_t)(b * S_) + s) * 2048 + h * 128;
    orow[lane] = (bf16)(a0 / l);
    orow[64 + lane] = (bf16)(a1 / l);
}

// ---------------------------------------------------------------------------
extern "C" void kernel_launch(void* const* d_in, const int* in_sizes, int n_in,
                              void* d_out, int out_size, void* d_ws, size_t ws_size,
                              hipStream_t stream) {
    const float* x        = (const float*)d_in[0];   // (4096, 2048) fp32
    const float* wq_a     = (const float*)d_in[1];   // (1536, 2048) fp32
    const float* q_norm_w = (const float*)d_in[2];   // (1536,) fp32
    const float* wq_b     = (const float*)d_in[3];   // (2048, 1536) fp32
    const float* wkv_a    = (const float*)d_in[4];   // (1088, 2048) fp32
    const float* kv_norm_w= (const float*)d_in[5];   // (1024,) fp32
    const float* wkv_b    = (const float*)d_in[6];   // (3072, 1024) fp32
    const float* wo       = (const float*)d_in[7];   // (2048, 2048) fp32
    const float* fcos     = (const float*)d_in[9];   // (2048, 32) fp32
    const float* fsin     = (const float*)d_in[10];  // (2048, 32) fp32
    float* out = (float*)d_out;                      // (4096, 2048) fp32

    char* ws = (char*)d_ws;
    bf16* kv2   = (bf16*)(ws);                  // (4096,3072) bf16 25.2MB
    bf16* kpe   = (bf16*)(ws + 25165824);       // (4096,64)   bf16 0.5MB
    bf16* kvb   = (bf16*)(ws + 25690112);       // (4096,1088) bf16 } region X
    bf16* qa    = (bf16*)(ws + 25690112);       // (4096,1536) bf16 } (time-
    bf16* attno = (bf16*)(ws + 25690112);       // (4096,2048) bf16 }  shared)
    bf16* qbuf  = (bf16*)d_out;                 // (4096,2048) bf16 in d_out

    dim3 blk(256);
    // ---- KV path (region X = kvb) ----
    gemm_bt<true, true, false><<<dim3(32, 9), blk, 0, stream>>>(x, wkv_a, kvb, 4096, 1088, 2048, 2048, 2048, 1088);
    rope_k<<<512, 256, 0, stream>>>(kvb, kpe, fcos, fsin);
    rmsnorm_ip<<<4096, 256, 0, stream>>>(kvb, kv_norm_w, 1024, 1088);
    gemm_bt<false, true, false><<<dim3(32, 24), blk, 0, stream>>>(kvb, wkv_b, kv2, 4096, 3072, 1024, 1088, 1024, 3072);
    // ---- Q path (region X = qa; qbuf in d_out) ----
    gemm_bt<true, true, false><<<dim3(32, 12), blk, 0, stream>>>(x, wq_a, qa, 4096, 1536, 2048, 2048, 2048, 1536);
    rmsnorm_ip<<<4096, 256, 0, stream>>>(qa, q_norm_w, 1536, 1536);
    gemm_bt<false, true, false><<<dim3(32, 16), blk, 0, stream>>>(qa, wq_b, qbuf, 4096, 2048, 1536, 1536, 1536, 2048);
    rope_q<<<8192, 256, 0, stream>>>(qbuf, fcos, fsin);
    // ---- attention (region X = attno) ----
    attn_simple<<<16384, 256, 0, stream>>>(qbuf, kv2, kpe, attno);
    // ---- output projection (fp32 store) ----
    gemm_bt<false, true, true><<<dim3(32, 16), blk, 0, stream>>>(attno, wo, out, 4096, 2048, 2048, 2048, 2048, 2048);
}

// Round 8
// 964.507 us; speedup vs baseline: 6.4805x; 6.4805x over previous
//
#include <hip/hip_runtime.h>
#include <hip/hip_bf16.h>

// MLA prefill: B=2,S=2048,D=2048,H=16,DQK=128(=64 nope+64 rope),DV=128,QLR=1536,KVLR=1024
// INPUTS ARE FP32 (reference setup_inputs dtypes); OUTPUT FP32.
// Compute in bf16 MFMA (fp32 accum); fp32->bf16 conversion fused into GEMM
// LDS staging. R8: MFMA flash attention replaces the SIMT bisect version
// (R7 counters: attn_simple = 6.4ms of 6.25ms total, MfmaUtil 0, VALU-bound).
// No __expf (container-killer). No INFINITY (finite-math safe).
//
// Workspace (42.5 MiB):
//   kv2  @ 0          (4096x3072 bf16, 25.2MB)   live: kv2-gemm .. attn
//   kpe  @ 25165824   (4096x64  bf16,  0.5MB)    live: rope_k .. attn
//   X    @ 25690112   (16.8MB region, time-shared)
//        kvb  (4096x1088 bf16)  live: kvb-gemm .. kv2-gemm
//        qa   (4096x1536 bf16)  live: qa-gemm .. qbuf-gemm
//        attno(4096x2048 bf16)  live: attn .. out-gemm
//   qbuf (4096x2048 bf16, 16.8MB) lives in d_out (33.5MB fp32) until out-gemm.

using bf16 = __hip_bfloat16;
typedef __attribute__((ext_vector_type(8))) short bf16x8;
typedef __attribute__((ext_vector_type(4))) float f32x4;

#define S_ 2048
#define NEG_BIG (-1e30f)

static __device__ __forceinline__ f32x4 mfma16(bf16x8 a, bf16x8 b, f32x4 c) {
    return __builtin_amdgcn_mfma_f32_16x16x32_bf16(a, b, c, 0, 0, 0);
}

// convert 8 contiguous fp32 -> 8 bf16 in registers
static __device__ __forceinline__ void cvt8(const float* __restrict__ p, bf16* __restrict__ dst) {
    float4 f0 = *(const float4*)p;
    float4 f1 = *(const float4*)(p + 4);
    dst[0] = (bf16)f0.x; dst[1] = (bf16)f0.y; dst[2] = (bf16)f0.z; dst[3] = (bf16)f0.w;
    dst[4] = (bf16)f1.x; dst[5] = (bf16)f1.y; dst[6] = (bf16)f1.z; dst[7] = (bf16)f1.w;
}

// ---------------------------------------------------------------------------
// GEMM: C[M,N] = A[M,K] @ B[N,K]^T. 128x128 tile, BK=32, 256 thr.
// A/B may be fp32 (converted to bf16 during LDS staging) or bf16.
// C stored fp32 or bf16. LDS XOR swizzle: chunkE = chunk ^ ((row>>1)&3).
// ---------------------------------------------------------------------------
template <bool A_F32, bool B_F32, bool C_F32>
__global__ __launch_bounds__(256) void gemm_bt(const void* __restrict__ Av,
                                               const void* __restrict__ Bv,
                                               void* __restrict__ Cv,
                                               int M, int N, int K,
                                               int lda, int ldb, int ldc) {
    __shared__ bf16 As[128 * 32];
    __shared__ bf16 Bs[128 * 32];
    const int tid = threadIdx.x;
    const int m0 = blockIdx.x * 128;
    const int n0 = blockIdx.y * 128;
    const int w = tid >> 6, lane = tid & 63, quad = lane >> 4, l15 = lane & 15;
    const int wr = (w >> 1) * 64, wc = (w & 1) * 64;

    f32x4 acc[4][4];
#pragma unroll
    for (int i = 0; i < 4; i++)
#pragma unroll
        for (int j = 0; j < 4; j++) acc[i][j] = (f32x4){0.f, 0.f, 0.f, 0.f};

    for (int k0 = 0; k0 < K; k0 += 32) {
        __syncthreads();
#pragma unroll
        for (int cc = 0; cc < 2; cc++) {
            int c = tid + cc * 256;          // 512 chunks of 8 elems
            int row = c >> 2;
            int chunk = c & 3;
            int chunkE = chunk ^ ((row >> 1) & 3);
            if (A_F32) {
                alignas(16) bf16 tmp[8];
                cvt8((const float*)Av + (size_t)(m0 + row) * lda + k0 + chunk * 8, tmp);
                *(int4*)(&As[row * 32 + chunkE * 8]) = *(const int4*)tmp;
            } else {
                int4 va = *(const int4*)((const bf16*)Av + (size_t)(m0 + row) * lda + k0 + chunk * 8);
                *(int4*)(&As[row * 32 + chunkE * 8]) = va;
            }
            if (n0 + row < N) {
                if (B_F32) {
                    alignas(16) bf16 tmp[8];
                    cvt8((const float*)Bv + (size_t)(n0 + row) * ldb + k0 + chunk * 8, tmp);
                    *(int4*)(&Bs[row * 32 + chunkE * 8]) = *(const int4*)tmp;
                } else {
                    int4 vb = *(const int4*)((const bf16*)Bv + (size_t)(n0 + row) * ldb + k0 + chunk * 8);
                    *(int4*)(&Bs[row * 32 + chunkE * 8]) = vb;
                }
            } else {
                *(int4*)(&Bs[row * 32 + chunkE * 8]) = (int4){0, 0, 0, 0};
            }
        }
        __syncthreads();
        bf16x8 af[4], bfr[4];
#pragma unroll
        for (int mi = 0; mi < 4; mi++) {
            int row = wr + mi * 16 + l15;
            int chunkE = quad ^ ((row >> 1) & 3);
            af[mi] = *(const bf16x8*)(&As[row * 32 + chunkE * 8]);
        }
#pragma unroll
        for (int ni = 0; ni < 4; ni++) {
            int row = wc + ni * 16 + l15;
            int chunkE = quad ^ ((row >> 1) & 3);
            bfr[ni] = *(const bf16x8*)(&Bs[row * 32 + chunkE * 8]);
        }
#pragma unroll
        for (int mi = 0; mi < 4; mi++)
#pragma unroll
            for (int ni = 0; ni < 4; ni++)
                acc[mi][ni] = mfma16(af[mi], bfr[ni], acc[mi][ni]);
    }

#pragma unroll
    for (int mi = 0; mi < 4; mi++) {
#pragma unroll
        for (int ni = 0; ni < 4; ni++) {
            int col = n0 + wc + ni * 16 + l15;
            if (col < N) {
#pragma unroll
                for (int r = 0; r < 4; r++) {
                    int row = m0 + wr + mi * 16 + quad * 4 + r;
                    if (C_F32) ((float*)Cv)[(size_t)row * ldc + col] = acc[mi][ni][r];
                    else       ((bf16*)Cv)[(size_t)row * ldc + col] = (bf16)acc[mi][ni][r];
                }
            }
        }
    }
}

// ---------------------------------------------------------------------------
// In-place row RMSNorm on bf16 buffer, fp32 weight, fp32 stats.
// ---------------------------------------------------------------------------
__global__ void rmsnorm_ip(bf16* __restrict__ buf, const float* __restrict__ w,
                           int cols, int ld) {
    int row = blockIdx.x;
    bf16* p = buf + (size_t)row * ld;
    float ss = 0.f;
    for (int c = threadIdx.x; c < cols; c += 256) {
        float v = __bfloat162float(p[c]);
        ss += v * v;
    }
#pragma unroll
    for (int off = 32; off; off >>= 1) ss += __shfl_down(ss, off, 64);
    __shared__ float red[4];
    __shared__ float rnorm_s;
    if ((threadIdx.x & 63) == 0) red[threadIdx.x >> 6] = ss;
    __syncthreads();
    if (threadIdx.x == 0)
        rnorm_s = rsqrtf((red[0] + red[1] + red[2] + red[3]) / cols + 1e-6f);
    __syncthreads();
    float rn = rnorm_s;
    for (int c = threadIdx.x; c < cols; c += 256) {
        float v = __bfloat162float(p[c]);
        p[c] = (bf16)(v * rn * w[c]);
    }
}

// ---------------------------------------------------------------------------
// RoPE on k_pe: kpe[row,0..64) = rope(kvb[row,1024..1088)). fp32 freqs.
// ---------------------------------------------------------------------------
__global__ void rope_k(const bf16* __restrict__ kvb, bf16* __restrict__ kpe,
                       const float* __restrict__ fc, const float* __restrict__ fs) {
    int id = blockIdx.x * 256 + threadIdx.x;  // ROWS*32
    int row = id >> 5, i = id & 31;
    int s = row & (S_ - 1);
    const bf16* p = kvb + (size_t)row * 1088 + 1024 + 2 * i;
    float x0 = __bfloat162float(p[0]), x1 = __bfloat162float(p[1]);
    float c = fc[s * 32 + i], sn = fs[s * 32 + i];
    bf16* q = kpe + (size_t)row * 64 + 2 * i;
    q[0] = (bf16)(x0 * c - x1 * sn);
    q[1] = (bf16)(x0 * sn + x1 * c);
}

// RoPE on q_pe, in-place on bf16 qbuf: [row, h*128+64 .. h*128+128)
__global__ void rope_q(bf16* __restrict__ qb, const float* __restrict__ fc,
                       const float* __restrict__ fs) {
    int id = blockIdx.x * 256 + threadIdx.x;  // ROWS*16*32
    int row = id >> 9, rest = id & 511, h = rest >> 5, i = rest & 31;
    int s = row & (S_ - 1);
    bf16* p = qb + (size_t)row * 2048 + h * 128 + 64 + 2 * i;
    float x0 = __bfloat162float(p[0]), x1 = __bfloat162float(p[1]);
    float c = fc[s * 32 + i], sn = fs[s * 32 + i];
    p[0] = (bf16)(x0 * c - x1 * sn);
    p[1] = (bf16)(x0 * sn + x1 * c);
}

// ---------------------------------------------------------------------------
// MFMA flash attention, causal. Block: 64 q-rows for one (b,h); 4 waves,
// 16 q-rows/wave. K/V tiles of 64 positions. K gathered from kv2(k_nope)+kpe;
// V staged transposed (Vt[dv][t]). LDS 8-chunk XOR swizzles.
// Softmax all-finite; plain expf.
// ---------------------------------------------------------------------------
__global__ __launch_bounds__(256) void attn_kernel(const bf16* __restrict__ Qg,
                                                   const bf16* __restrict__ KV2,
                                                   const bf16* __restrict__ KPE,
                                                   bf16* __restrict__ Og) {
    __shared__ bf16 Ks[64 * 128];       // [t][d] (swizzled)
    __shared__ bf16 Vt[128 * 64];       // [dv][t] (swizzled)
    __shared__ bf16 Ps[4 * 16 * 64];    // per-wave P [m][t] (swizzled)
    const int tid = threadIdx.x;
    const int q0 = blockIdx.x * 64;
    const int h = blockIdx.y;
    const int b = blockIdx.z;
    const int w = tid >> 6, lane = tid & 63, quad = lane >> 4, l15 = lane & 15;
    const float scale = 0.08838834764831845f;  // 1/sqrt(128)

    // Q A-frags straight from global (read once): A[m=l15][k=quad*8+j]
    bf16x8 qf[4];
    {
        const bf16* qp = Qg + ((size_t)(b * S_) + q0 + w * 16 + l15) * 2048 + h * 128 + quad * 8;
#pragma unroll
        for (int kk = 0; kk < 4; kk++) qf[kk] = *(const bf16x8*)(qp + kk * 32);
    }

    f32x4 acc_o[8];
#pragma unroll
    for (int j = 0; j < 8; j++) acc_o[j] = (f32x4){0.f, 0.f, 0.f, 0.f};
    float m_i[4], l_i[4];
#pragma unroll
    for (int r = 0; r < 4; r++) { m_i[r] = NEG_BIG; l_i[r] = 0.f; }
    const int s_base = q0 + w * 16 + quad * 4;  // + r = global q row

    for (int t0 = 0; t0 <= q0 + 63; t0 += 64) {
        __syncthreads();  // prev iter's Ks/Vt/Ps reads done
        // stage K: 64 x 128 = 1024 chunks of 8
#pragma unroll
        for (int cc = 0; cc < 4; cc++) {
            int c = tid + cc * 256;
            int trow = c >> 4, chunk = c & 15;
            int col8 = chunk * 8;
            size_t grow = (size_t)(b * S_) + t0 + trow;
            int4 v;
            if (col8 < 64) v = *(const int4*)(KV2 + grow * 3072 + h * 192 + col8);
            else           v = *(const int4*)(KPE + grow * 64 + col8 - 64);
            int chunkE = chunk ^ (trow & 7);
            *(int4*)(&Ks[trow * 128 + chunkE * 8]) = v;
        }
        // stage V transposed
#pragma unroll
        for (int cc = 0; cc < 4; cc++) {
            int c = tid + cc * 256;
            int t = c & 63, dv0 = (c >> 6) * 8;
            size_t grow = (size_t)(b * S_) + t0 + t;
            alignas(16) bf16 vals[8];
            *(int4*)vals = *(const int4*)(KV2 + grow * 3072 + h * 192 + 64 + dv0);
            int chunk = t >> 3, tl = t & 7;
#pragma unroll
            for (int j = 0; j < 8; j++) {
                int dv = dv0 + j;
                Vt[dv * 64 + (chunk ^ (dv & 7)) * 8 + tl] = vals[j];
            }
        }
        __syncthreads();

        // scores: S = Q K^T  (m = q-row, n = t)
        f32x4 sc[4];
#pragma unroll
        for (int ni = 0; ni < 4; ni++) sc[ni] = (f32x4){0.f, 0.f, 0.f, 0.f};
#pragma unroll
        for (int kk = 0; kk < 4; kk++) {
#pragma unroll
            for (int ni = 0; ni < 4; ni++) {
                int trow = ni * 16 + l15;
                int chunkE = (kk * 4 + quad) ^ (trow & 7);
                bf16x8 kf = *(const bf16x8*)(&Ks[trow * 128 + chunkE * 8]);
                sc[ni] = mfma16(qf[kk], kf, sc[ni]);
            }
        }
        // scale + causal mask + online softmax (all-finite)
        float pv[4][4], rmax[4];
#pragma unroll
        for (int r = 0; r < 4; r++) rmax[r] = NEG_BIG;
#pragma unroll
        for (int ni = 0; ni < 4; ni++) {
            int t = t0 + ni * 16 + l15;
#pragma unroll
            for (int r = 0; r < 4; r++) {
                float x = sc[ni][r] * scale;
                if (t > s_base + r) x = NEG_BIG;
                pv[ni][r] = x;
                rmax[r] = fmaxf(rmax[r], x);
            }
        }
#pragma unroll
        for (int r = 0; r < 4; r++) {
            rmax[r] = fmaxf(rmax[r], __shfl_xor(rmax[r], 1, 64));
            rmax[r] = fmaxf(rmax[r], __shfl_xor(rmax[r], 2, 64));
            rmax[r] = fmaxf(rmax[r], __shfl_xor(rmax[r], 4, 64));
            rmax[r] = fmaxf(rmax[r], __shfl_xor(rmax[r], 8, 64));
        }
        float alpha[4], rsum[4];
#pragma unroll
        for (int r = 0; r < 4; r++) {
            float mn = fmaxf(m_i[r], rmax[r]);
            alpha[r] = expf(m_i[r] - mn);
            m_i[r] = mn;
            rsum[r] = 0.f;
        }
#pragma unroll
        for (int ni = 0; ni < 4; ni++)
#pragma unroll
            for (int r = 0; r < 4; r++) {
                float e = expf(pv[ni][r] - m_i[r]);
                pv[ni][r] = e;
                rsum[r] += e;
            }
#pragma unroll
        for (int r = 0; r < 4; r++) {
            rsum[r] += __shfl_xor(rsum[r], 1, 64);
            rsum[r] += __shfl_xor(rsum[r], 2, 64);
            rsum[r] += __shfl_xor(rsum[r], 4, 64);
            rsum[r] += __shfl_xor(rsum[r], 8, 64);
            l_i[r] = l_i[r] * alpha[r] + rsum[r];
        }
#pragma unroll
        for (int nj = 0; nj < 8; nj++)
#pragma unroll
            for (int r = 0; r < 4; r++) acc_o[nj][r] *= alpha[r];

        // P (C-layout) -> LDS (A-layout source), bf16
#pragma unroll
        for (int ni = 0; ni < 4; ni++) {
            int tl = ni * 16 + l15;
            int chunk = tl >> 3;
#pragma unroll
            for (int r = 0; r < 4; r++) {
                int m = quad * 4 + r;
                Ps[w * 1024 + m * 64 + (chunk ^ (m & 7)) * 8 + (tl & 7)] = (bf16)pv[ni][r];
            }
        }
        __syncthreads();
        // O += P @ V
#pragma unroll
        for (int kk2 = 0; kk2 < 2; kk2++) {
            int chunkE_p = (kk2 * 4 + quad) ^ (l15 & 7);
            bf16x8 pf = *(const bf16x8*)(&Ps[w * 1024 + l15 * 64 + chunkE_p * 8]);
#pragma unroll
            for (int nj = 0; nj < 8; nj++) {
                int dv = nj * 16 + l15;
                int chunkE = (kk2 * 4 + quad) ^ (dv & 7);
                bf16x8 vf = *(const bf16x8*)(&Vt[dv * 64 + chunkE * 8]);
                acc_o[nj] = mfma16(pf, vf, acc_o[nj]);
            }
        }
    }
    // epilogue: O / l
#pragma unroll
    for (int nj = 0; nj < 8; nj++) {
        int col = h * 128 + nj * 16 + l15;
#pragma unroll
        for (int r = 0; r < 4; r++) {
            float v = acc_o[nj][r] / l_i[r];
            Og[((size_t)(b * S_) + s_base + r) * 2048 + col] = (bf16)v;
        }
    }
}

// ---------------------------------------------------------------------------
extern "C" void kernel_launch(void* const* d_in, const int* in_sizes, int n_in,
                              void* d_out, int out_size, void* d_ws, size_t ws_size,
                              hipStream_t stream) {
    const float* x        = (const float*)d_in[0];   // (4096, 2048) fp32
    const float* wq_a     = (const float*)d_in[1];   // (1536, 2048) fp32
    const float* q_norm_w = (const float*)d_in[2];   // (1536,) fp32
    const float* wq_b     = (const float*)d_in[3];   // (2048, 1536) fp32
    const float* wkv_a    = (const float*)d_in[4];   // (1088, 2048) fp32
    const float* kv_norm_w= (const float*)d_in[5];   // (1024,) fp32
    const float* wkv_b    = (const float*)d_in[6];   // (3072, 1024) fp32
    const float* wo       = (const float*)d_in[7];   // (2048, 2048) fp32
    const float* fcos     = (const float*)d_in[9];   // (2048, 32) fp32
    const float* fsin     = (const float*)d_in[10];  // (2048, 32) fp32
    float* out = (float*)d_out;                      // (4096, 2048) fp32

    char* ws = (char*)d_ws;
    bf16* kv2   = (bf16*)(ws);                  // (4096,3072) bf16 25.2MB
    bf16* kpe   = (bf16*)(ws + 25165824);       // (4096,64)   bf16 0.5MB
    bf16* kvb   = (bf16*)(ws + 25690112);       // (4096,1088) bf16 } region X
    bf16* qa    = (bf16*)(ws + 25690112);       // (4096,1536) bf16 } (time-
    bf16* attno = (bf16*)(ws + 25690112);       // (4096,2048) bf16 }  shared)
    bf16* qbuf  = (bf16*)d_out;                 // (4096,2048) bf16 in d_out

    dim3 blk(256);
    // ---- KV path (region X = kvb) ----
    gemm_bt<true, true, false><<<dim3(32, 9), blk, 0, stream>>>(x, wkv_a, kvb, 4096, 1088, 2048, 2048, 2048, 1088);
    rope_k<<<512, 256, 0, stream>>>(kvb, kpe, fcos, fsin);
    rmsnorm_ip<<<4096, 256, 0, stream>>>(kvb, kv_norm_w, 1024, 1088);
    gemm_bt<false, true, false><<<dim3(32, 24), blk, 0, stream>>>(kvb, wkv_b, kv2, 4096, 3072, 1024, 1088, 1024, 3072);
    // ---- Q path (region X = qa; qbuf in d_out) ----
    gemm_bt<true, true, false><<<dim3(32, 12), blk, 0, stream>>>(x, wq_a, qa, 4096, 1536, 2048, 2048, 2048, 1536);
    rmsnorm_ip<<<4096, 256, 0, stream>>>(qa, q_norm_w, 1536, 1536);
    gemm_bt<false, true, false><<<dim3(32, 16), blk, 0, stream>>>(qa, wq_b, qbuf, 4096, 2048, 1536, 1536, 1536, 2048);
    rope_q<<<8192, 256, 0, stream>>>(qbuf, fcos, fsin);
    // ---- attention (MFMA flash; region X = attno) ----
    attn_kernel<<<dim3(32, 16, 2), blk, 0, stream>>>(qbuf, kv2, kpe, attno);
    // ---- output projection (fp32 store) ----
    gemm_bt<false, true, true><<<dim3(32, 16), blk, 0, stream>>>(attno, wo, out, 4096, 2048, 2048, 2048, 2048, 2048);
}

// Round 9
// 725.946 us; speedup vs baseline: 8.6101x; 1.3286x over previous
//
#include <hip/hip_runtime.h>
#include <hip/hip_bf16.h>

// MLA prefill: B=2,S=2048,D=2048,H=16,DQK=128(=64 nope+64 rope),DV=128,QLR=1536,KVLR=1024
// INPUTS FP32; OUTPUT FP32. R9: pre-convert x + weights to bf16 once, all
// GEMMs pure-bf16 staging (m93 pattern); exp2f softmax (pre-scaled by log2e).
// No __expf (container-killer). No INFINITY (finite-math safe).
//
// Workspace (67.7 MiB; 80MB proven writable in R1):
//   kv2 @ 0         (4096x3072 bf16, 25.2MB)  live: kv2-gemm .. attn
//   kpe @ 25165824  (4096x64  bf16,  0.5MB)   live: rope_k .. attn
//   X   @ 25690112  (16.8MB, time-shared): kvb -> qa -> attno
//   xb  @ 43319296  (4096x2048 bf16, 16.8MB)  live: cvt .. qa-gemm
//   W   @ 60096512  (8.4MB weight slot, reused: wkv_a,wkv_b,wq_a,wq_b,wo)
//   qbuf (4096x2048 bf16) lives in d_out until out-gemm.

using bf16 = __hip_bfloat16;
typedef __attribute__((ext_vector_type(8))) short bf16x8;
typedef __attribute__((ext_vector_type(4))) float f32x4;

#define S_ 2048
#define NEG_BIG (-1e30f)
#define LOG2E 1.4426950408889634f

static __device__ __forceinline__ f32x4 mfma16(bf16x8 a, bf16x8 b, f32x4 c) {
    return __builtin_amdgcn_mfma_f32_16x16x32_bf16(a, b, c, 0, 0, 0);
}

// ---------------------------------------------------------------------------
// fp32 -> bf16 bulk convert, 4 elems/thread.
// ---------------------------------------------------------------------------
__global__ __launch_bounds__(256) void f2b(const float* __restrict__ src,
                                           bf16* __restrict__ dst, int n4) {
    int i = blockIdx.x * 256 + threadIdx.x;
    if (i < n4) {
        float4 v = ((const float4*)src)[i];
        alignas(8) bf16 t[4];
        t[0] = (bf16)v.x; t[1] = (bf16)v.y; t[2] = (bf16)v.z; t[3] = (bf16)v.w;
        ((uint2*)dst)[i] = *(const uint2*)t;
    }
}

// ---------------------------------------------------------------------------
// GEMM: C[M,N] = A[M,K] @ B[N,K]^T. 128x128 tile, BK=32, 256 thr, bf16 in.
// C stored fp32 or bf16. LDS XOR swizzle: chunkE = chunk ^ ((row>>1)&3).
// ---------------------------------------------------------------------------
template <bool C_F32>
__global__ __launch_bounds__(256) void gemm_bt(const bf16* __restrict__ A,
                                               const bf16* __restrict__ Bw,
                                               void* __restrict__ Cv,
                                               int M, int N, int K,
                                               int lda, int ldb, int ldc) {
    __shared__ bf16 As[128 * 32];
    __shared__ bf16 Bs[128 * 32];
    const int tid = threadIdx.x;
    const int m0 = blockIdx.x * 128;
    const int n0 = blockIdx.y * 128;
    const int w = tid >> 6, lane = tid & 63, quad = lane >> 4, l15 = lane & 15;
    const int wr = (w >> 1) * 64, wc = (w & 1) * 64;

    f32x4 acc[4][4];
#pragma unroll
    for (int i = 0; i < 4; i++)
#pragma unroll
        for (int j = 0; j < 4; j++) acc[i][j] = (f32x4){0.f, 0.f, 0.f, 0.f};

    for (int k0 = 0; k0 < K; k0 += 32) {
        __syncthreads();
#pragma unroll
        for (int cc = 0; cc < 2; cc++) {
            int c = tid + cc * 256;          // 512 chunks of 8 elems
            int row = c >> 2;
            int chunk = c & 3;
            int chunkE = chunk ^ ((row >> 1) & 3);
            int4 va = *(const int4*)(A + (size_t)(m0 + row) * lda + k0 + chunk * 8);
            *(int4*)(&As[row * 32 + chunkE * 8]) = va;
            int4 vb = {0, 0, 0, 0};
            if (n0 + row < N)
                vb = *(const int4*)(Bw + (size_t)(n0 + row) * ldb + k0 + chunk * 8);
            *(int4*)(&Bs[row * 32 + chunkE * 8]) = vb;
        }
        __syncthreads();
        bf16x8 af[4], bfr[4];
#pragma unroll
        for (int mi = 0; mi < 4; mi++) {
            int row = wr + mi * 16 + l15;
            int chunkE = quad ^ ((row >> 1) & 3);
            af[mi] = *(const bf16x8*)(&As[row * 32 + chunkE * 8]);
        }
#pragma unroll
        for (int ni = 0; ni < 4; ni++) {
            int row = wc + ni * 16 + l15;
            int chunkE = quad ^ ((row >> 1) & 3);
            bfr[ni] = *(const bf16x8*)(&Bs[row * 32 + chunkE * 8]);
        }
#pragma unroll
        for (int mi = 0; mi < 4; mi++)
#pragma unroll
            for (int ni = 0; ni < 4; ni++)
                acc[mi][ni] = mfma16(af[mi], bfr[ni], acc[mi][ni]);
    }

#pragma unroll
    for (int mi = 0; mi < 4; mi++) {
#pragma unroll
        for (int ni = 0; ni < 4; ni++) {
            int col = n0 + wc + ni * 16 + l15;
            if (col < N) {
#pragma unroll
                for (int r = 0; r < 4; r++) {
                    int row = m0 + wr + mi * 16 + quad * 4 + r;
                    if (C_F32) ((float*)Cv)[(size_t)row * ldc + col] = acc[mi][ni][r];
                    else       ((bf16*)Cv)[(size_t)row * ldc + col] = (bf16)acc[mi][ni][r];
                }
            }
        }
    }
}

// ---------------------------------------------------------------------------
// In-place row RMSNorm on bf16 buffer, fp32 weight, fp32 stats.
// ---------------------------------------------------------------------------
__global__ void rmsnorm_ip(bf16* __restrict__ buf, const float* __restrict__ w,
                           int cols, int ld) {
    int row = blockIdx.x;
    bf16* p = buf + (size_t)row * ld;
    float ss = 0.f;
    for (int c = threadIdx.x; c < cols; c += 256) {
        float v = __bfloat162float(p[c]);
        ss += v * v;
    }
#pragma unroll
    for (int off = 32; off; off >>= 1) ss += __shfl_down(ss, off, 64);
    __shared__ float red[4];
    __shared__ float rnorm_s;
    if ((threadIdx.x & 63) == 0) red[threadIdx.x >> 6] = ss;
    __syncthreads();
    if (threadIdx.x == 0)
        rnorm_s = rsqrtf((red[0] + red[1] + red[2] + red[3]) / cols + 1e-6f);
    __syncthreads();
    float rn = rnorm_s;
    for (int c = threadIdx.x; c < cols; c += 256) {
        float v = __bfloat162float(p[c]);
        p[c] = (bf16)(v * rn * w[c]);
    }
}

// ---------------------------------------------------------------------------
// RoPE on k_pe: kpe[row,0..64) = rope(kvb[row,1024..1088)). fp32 freqs.
// ---------------------------------------------------------------------------
__global__ void rope_k(const bf16* __restrict__ kvb, bf16* __restrict__ kpe,
                       const float* __restrict__ fc, const float* __restrict__ fs) {
    int id = blockIdx.x * 256 + threadIdx.x;  // ROWS*32
    int row = id >> 5, i = id & 31;
    int s = row & (S_ - 1);
    const bf16* p = kvb + (size_t)row * 1088 + 1024 + 2 * i;
    float x0 = __bfloat162float(p[0]), x1 = __bfloat162float(p[1]);
    float c = fc[s * 32 + i], sn = fs[s * 32 + i];
    bf16* q = kpe + (size_t)row * 64 + 2 * i;
    q[0] = (bf16)(x0 * c - x1 * sn);
    q[1] = (bf16)(x0 * sn + x1 * c);
}

// RoPE on q_pe, in-place on bf16 qbuf: [row, h*128+64 .. h*128+128)
__global__ void rope_q(bf16* __restrict__ qb, const float* __restrict__ fc,
                       const float* __restrict__ fs) {
    int id = blockIdx.x * 256 + threadIdx.x;  // ROWS*16*32
    int row = id >> 9, rest = id & 511, h = rest >> 5, i = rest & 31;
    int s = row & (S_ - 1);
    bf16* p = qb + (size_t)row * 2048 + h * 128 + 64 + 2 * i;
    float x0 = __bfloat162float(p[0]), x1 = __bfloat162float(p[1]);
    float c = fc[s * 32 + i], sn = fs[s * 32 + i];
    p[0] = (bf16)(x0 * c - x1 * sn);
    p[1] = (bf16)(x0 * sn + x1 * c);
}

// ---------------------------------------------------------------------------
// MFMA flash attention, causal. 64 q-rows per block (one b,h); 4 waves.
// K/V tiles of 64. Softmax in base-2: scores pre-scaled by scale*log2e,
// exp2f for p and alpha (thin v_exp_f32 wrapper — NOT __expf).
// ---------------------------------------------------------------------------
__global__ __launch_bounds__(256) void attn_kernel(const bf16* __restrict__ Qg,
                                                   const bf16* __restrict__ KV2,
                                                   const bf16* __restrict__ KPE,
                                                   bf16* __restrict__ Og) {
    __shared__ bf16 Ks[64 * 128];       // [t][d] (swizzled)
    __shared__ bf16 Vt[128 * 64];       // [dv][t] (swizzled)
    __shared__ bf16 Ps[4 * 16 * 64];    // per-wave P [m][t] (swizzled)
    const int tid = threadIdx.x;
    const int q0 = blockIdx.x * 64;
    const int h = blockIdx.y;
    const int b = blockIdx.z;
    const int w = tid >> 6, lane = tid & 63, quad = lane >> 4, l15 = lane & 15;
    const float scl2 = 0.08838834764831845f * LOG2E;  // 1/sqrt(128) * log2(e)

    bf16x8 qf[4];
    {
        const bf16* qp = Qg + ((size_t)(b * S_) + q0 + w * 16 + l15) * 2048 + h * 128 + quad * 8;
#pragma unroll
        for (int kk = 0; kk < 4; kk++) qf[kk] = *(const bf16x8*)(qp + kk * 32);
    }

    f32x4 acc_o[8];
#pragma unroll
    for (int j = 0; j < 8; j++) acc_o[j] = (f32x4){0.f, 0.f, 0.f, 0.f};
    float m_i[4], l_i[4];
#pragma unroll
    for (int r = 0; r < 4; r++) { m_i[r] = NEG_BIG; l_i[r] = 0.f; }
    const int s_base = q0 + w * 16 + quad * 4;

    for (int t0 = 0; t0 <= q0 + 63; t0 += 64) {
        __syncthreads();
        // stage K: 64 x 128 = 1024 chunks of 8
#pragma unroll
        for (int cc = 0; cc < 4; cc++) {
            int c = tid + cc * 256;
            int trow = c >> 4, chunk = c & 15;
            int col8 = chunk * 8;
            size_t grow = (size_t)(b * S_) + t0 + trow;
            int4 v;
            if (col8 < 64) v = *(const int4*)(KV2 + grow * 3072 + h * 192 + col8);
            else           v = *(const int4*)(KPE + grow * 64 + col8 - 64);
            int chunkE = chunk ^ (trow & 7);
            *(int4*)(&Ks[trow * 128 + chunkE * 8]) = v;
        }
        // stage V transposed
#pragma unroll
        for (int cc = 0; cc < 4; cc++) {
            int c = tid + cc * 256;
            int t = c & 63, dv0 = (c >> 6) * 8;
            size_t grow = (size_t)(b * S_) + t0 + t;
            alignas(16) bf16 vals[8];
            *(int4*)vals = *(const int4*)(KV2 + grow * 3072 + h * 192 + 64 + dv0);
            int chunk = t >> 3, tl = t & 7;
#pragma unroll
            for (int j = 0; j < 8; j++) {
                int dv = dv0 + j;
                Vt[dv * 64 + (chunk ^ (dv & 7)) * 8 + tl] = vals[j];
            }
        }
        __syncthreads();

        // scores: S = Q K^T
        f32x4 sc[4];
#pragma unroll
        for (int ni = 0; ni < 4; ni++) sc[ni] = (f32x4){0.f, 0.f, 0.f, 0.f};
#pragma unroll
        for (int kk = 0; kk < 4; kk++) {
#pragma unroll
            for (int ni = 0; ni < 4; ni++) {
                int trow = ni * 16 + l15;
                int chunkE = (kk * 4 + quad) ^ (trow & 7);
                bf16x8 kf = *(const bf16x8*)(&Ks[trow * 128 + chunkE * 8]);
                sc[ni] = mfma16(qf[kk], kf, sc[ni]);
            }
        }
        // base-2 online softmax (all-finite)
        float pv[4][4], rmax[4];
#pragma unroll
        for (int r = 0; r < 4; r++) rmax[r] = NEG_BIG;
#pragma unroll
        for (int ni = 0; ni < 4; ni++) {
            int t = t0 + ni * 16 + l15;
#pragma unroll
            for (int r = 0; r < 4; r++) {
                float x = sc[ni][r] * scl2;
                if (t > s_base + r) x = NEG_BIG;
                pv[ni][r] = x;
                rmax[r] = fmaxf(rmax[r], x);
            }
        }
#pragma unroll
        for (int r = 0; r < 4; r++) {
            rmax[r] = fmaxf(rmax[r], __shfl_xor(rmax[r], 1, 64));
            rmax[r] = fmaxf(rmax[r], __shfl_xor(rmax[r], 2, 64));
            rmax[r] = fmaxf(rmax[r], __shfl_xor(rmax[r], 4, 64));
            rmax[r] = fmaxf(rmax[r], __shfl_xor(rmax[r], 8, 64));
        }
        float alpha[4], rsum[4];
#pragma unroll
        for (int r = 0; r < 4; r++) {
            float mn = fmaxf(m_i[r], rmax[r]);
            alpha[r] = exp2f(m_i[r] - mn);
            m_i[r] = mn;
            rsum[r] = 0.f;
        }
#pragma unroll
        for (int ni = 0; ni < 4; ni++)
#pragma unroll
            for (int r = 0; r < 4; r++) {
                float e = exp2f(pv[ni][r] - m_i[r]);
                pv[ni][r] = e;
                rsum[r] += e;
            }
#pragma unroll
        for (int r = 0; r < 4; r++) {
            rsum[r] += __shfl_xor(rsum[r], 1, 64);
            rsum[r] += __shfl_xor(rsum[r], 2, 64);
            rsum[r] += __shfl_xor(rsum[r], 4, 64);
            rsum[r] += __shfl_xor(rsum[r], 8, 64);
            l_i[r] = l_i[r] * alpha[r] + rsum[r];
        }
#pragma unroll
        for (int nj = 0; nj < 8; nj++)
#pragma unroll
            for (int r = 0; r < 4; r++) acc_o[nj][r] *= alpha[r];

        // P (C-layout) -> LDS (A-layout source), bf16
#pragma unroll
        for (int ni = 0; ni < 4; ni++) {
            int tl = ni * 16 + l15;
            int chunk = tl >> 3;
#pragma unroll
            for (int r = 0; r < 4; r++) {
                int m = quad * 4 + r;
                Ps[w * 1024 + m * 64 + (chunk ^ (m & 7)) * 8 + (tl & 7)] = (bf16)pv[ni][r];
            }
        }
        __syncthreads();
        // O += P @ V
#pragma unroll
        for (int kk2 = 0; kk2 < 2; kk2++) {
            int chunkE_p = (kk2 * 4 + quad) ^ (l15 & 7);
            bf16x8 pf = *(const bf16x8*)(&Ps[w * 1024 + l15 * 64 + chunkE_p * 8]);
#pragma unroll
            for (int nj = 0; nj < 8; nj++) {
                int dv = nj * 16 + l15;
                int chunkE = (kk2 * 4 + quad) ^ (dv & 7);
                bf16x8 vf = *(const bf16x8*)(&Vt[dv * 64 + chunkE * 8]);
                acc_o[nj] = mfma16(pf, vf, acc_o[nj]);
            }
        }
    }
    // epilogue
#pragma unroll
    for (int nj = 0; nj < 8; nj++) {
        int col = h * 128 + nj * 16 + l15;
#pragma unroll
        for (int r = 0; r < 4; r++) {
            float v = acc_o[nj][r] / l_i[r];
            Og[((size_t)(b * S_) + s_base + r) * 2048 + col] = (bf16)v;
        }
    }
}

// ---------------------------------------------------------------------------
extern "C" void kernel_launch(void* const* d_in, const int* in_sizes, int n_in,
                              void* d_out, int out_size, void* d_ws, size_t ws_size,
                              hipStream_t stream) {
    const float* x        = (const float*)d_in[0];   // (4096, 2048) fp32
    const float* wq_a     = (const float*)d_in[1];   // (1536, 2048) fp32
    const float* q_norm_w = (const float*)d_in[2];   // (1536,) fp32
    const float* wq_b     = (const float*)d_in[3];   // (2048, 1536) fp32
    const float* wkv_a    = (const float*)d_in[4];   // (1088, 2048) fp32
    const float* kv_norm_w= (const float*)d_in[5];   // (1024,) fp32
    const float* wkv_b    = (const float*)d_in[6];   // (3072, 1024) fp32
    const float* wo       = (const float*)d_in[7];   // (2048, 2048) fp32
    const float* fcos     = (const float*)d_in[9];   // (2048, 32) fp32
    const float* fsin     = (const float*)d_in[10];  // (2048, 32) fp32
    float* out = (float*)d_out;                      // (4096, 2048) fp32

    char* ws = (char*)d_ws;
    bf16* kv2   = (bf16*)(ws);                  // 25.2MB
    bf16* kpe   = (bf16*)(ws + 25165824);       // 0.5MB
    bf16* kvb   = (bf16*)(ws + 25690112);       // } region X (16.8MB,
    bf16* qa    = (bf16*)(ws + 25690112);       // }  time-shared)
    bf16* attno = (bf16*)(ws + 25690112);       // }
    bf16* xb    = (bf16*)(ws + 43319296);       // 16.8MB
    bf16* wslot = (bf16*)(ws + 60096512);       // 8.4MB reusable weight slot
    bf16* qbuf  = (bf16*)d_out;                 // bf16 in d_out

    dim3 blk(256);
    // ---- convert x once ----
    f2b<<<8192, blk, 0, stream>>>(x, xb, 2097152);
    // ---- KV path ----
    f2b<<<2176, blk, 0, stream>>>(wkv_a, wslot, 557056);   // 1088*2048/4
    gemm_bt<false><<<dim3(32, 9), blk, 0, stream>>>(xb, wslot, kvb, 4096, 1088, 2048, 2048, 2048, 1088);
    rope_k<<<512, blk, 0, stream>>>(kvb, kpe, fcos, fsin);
    rmsnorm_ip<<<4096, blk, 0, stream>>>(kvb, kv_norm_w, 1024, 1088);
    f2b<<<3072, blk, 0, stream>>>(wkv_b, wslot, 786432);   // 3072*1024/4
    gemm_bt<false><<<dim3(32, 24), blk, 0, stream>>>(kvb, wslot, kv2, 4096, 3072, 1024, 1088, 1024, 3072);
    // ---- Q path (region X becomes qa; qbuf in d_out) ----
    f2b<<<3072, blk, 0, stream>>>(wq_a, wslot, 786432);    // 1536*2048/4
    gemm_bt<false><<<dim3(32, 12), blk, 0, stream>>>(xb, wslot, qa, 4096, 1536, 2048, 2048, 2048, 1536);
    rmsnorm_ip<<<4096, blk, 0, stream>>>(qa, q_norm_w, 1536, 1536);
    f2b<<<3072, blk, 0, stream>>>(wq_b, wslot, 786432);    // 2048*1536/4
    gemm_bt<false><<<dim3(32, 16), blk, 0, stream>>>(qa, wslot, qbuf, 4096, 2048, 1536, 1536, 1536, 2048);
    rope_q<<<8192, blk, 0, stream>>>(qbuf, fcos, fsin);
    // ---- attention (region X becomes attno) ----
    attn_kernel<<<dim3(32, 16, 2), blk, 0, stream>>>(qbuf, kv2, kpe, attno);
    // ---- output projection (fp32 store) ----
    f2b<<<4096, blk, 0, stream>>>(wo, wslot, 1048576);     // 2048*2048/4
    gemm_bt<true><<<dim3(32, 16), blk, 0, stream>>>(attno, wslot, out, 4096, 2048, 2048, 2048, 2048, 2048);
}